// Round 1
// baseline (107.395 us; speedup 1.0000x reference)
//
#include <hip/hip_runtime.h>
#include <math.h>

#define NCLS 80
#define NB 16
#define NA 3
#define NT 100

// grid-cell state layout: scale0 (80x80) cells [0,102400), scale1 (40x40)
// [102400,128000), scale2 (20x20) [128000,134400). index = off[s] + b*HW + j*W + i
static constexpr int TOTCELLS  = 134400;
static constexpr int CELL_OFF1 = 102400;
static constexpr int CELL_OFF2 = 128000;

// obj-channel element space: scale0 [0,307200), scale1 [,384000), scale2 [,403200)
static constexpr int OBJ_TOT  = 403200;
static constexpr int OBJ_OFF1 = 307200;
static constexpr int OBJ_OFF2 = 384000;

__device__ unsigned g_lastMain[TOTCELLS];   // (t+1) of last valid MAIN event, 0 = none
__device__ unsigned g_lastAny [TOTCELLS];   // (t+1) of last event of any kind, 0 = none
__device__ unsigned g_maskA   [TOTCELLS*3]; // 80-bit class OR mask
__device__ float4   g_bvec  [NB*NT];        // clipped box per target
__device__ float    g_weight[NB*NT];        // weight per target
__device__ double   g_objsum[3];
__device__ double   g_boxsum[3];
__device__ double   g_clssum[3];
__device__ unsigned g_npos  [3];

__device__ __forceinline__ float softplusf(float x) {
    // logaddexp(0,x) stable
    return fmaxf(x, 0.0f) + log1pf(expf(-fabsf(x)));
}

__global__ __launch_bounds__(256) void k_clear() {
    int i = blockIdx.x * 256 + threadIdx.x;  // grid = 525*256 = 134400 exactly
    g_lastMain[i] = 0u;
    g_lastAny[i]  = 0u;
    g_maskA[3*i+0] = 0u; g_maskA[3*i+1] = 0u; g_maskA[3*i+2] = 0u;
    if (i < 3) { g_objsum[i] = 0.0; g_boxsum[i] = 0.0; g_clssum[i] = 0.0; g_npos[i] = 0u; }
}

// One thread per (b,t). Order-faithful via atomicMax on sequence = t+1.
__global__ __launch_bounds__(256) void k_scatter(const float* __restrict__ tgt) {
    int idx = blockIdx.x * 256 + threadIdx.x;
    if (idx >= NB * NT) return;
    int b = idx / NT, t = idx % NT;
    const float* p = tgt + (size_t)idx * 5;
    float x1 = fminf(fmaxf(p[0], 0.0f), 1.0f);
    float y1 = fminf(fmaxf(p[1], 0.0f), 1.0f);
    float x2 = fminf(fmaxf(p[2], 0.0f), 1.0f);
    float y2 = fminf(fmaxf(p[3], 0.0f), 1.0f);
    bool valid = (x2 > x1) && (y2 > y1);
    float area = (x2 - x1) * (y2 - y1);
    int sidx = (area <= 0.0025f) ? 0 : ((area <= 0.0225f) ? 1 : 2);
    int Wd = (sidx == 0) ? 80 : ((sidx == 1) ? 40 : 20);
    int HWc = Wd * Wd;
    int soff = (sidx == 0) ? 0 : ((sidx == 1) ? CELL_OFF1 : CELL_OFF2);

    int gi = (int)floorf(0.5f * (x1 + x2) * (float)Wd);
    int gj = (int)floorf(0.5f * (y1 + y2) * (float)Wd);
    gi = min(max(gi, 0), Wd - 1);
    gj = min(max(gj, 0), Wd - 1);

    int cid = (int)p[4];
    bool cls_ok = (cid >= 0) && (cid < NCLS);
    float smallness = 1.0f - fminf(1.0f, area / 0.0025f);
    float weight = 1.0f + fmaxf(0.0f, smallness);

    g_bvec[idx]   = make_float4(x1, y1, x2, y2);
    g_weight[idx] = weight;

    if (!valid) return;
    unsigned seq = (unsigned)(t + 1);
    int cell = soff + b * HWc + gj * Wd + gi;
    atomicMax(&g_lastMain[cell], seq);
    atomicMax(&g_lastAny[cell],  seq);
    if (cls_ok) atomicOr(&g_maskA[3*cell + (cid >> 5)], 1u << (cid & 31));

    if (area <= 0.0025f) {  // tiny -> 4 neighbors
        const int dj[4] = {-1, 1, 0, 0};
        const int di[4] = {0, 0, -1, 1};
        #pragma unroll
        for (int k = 0; k < 4; ++k) {
            int nj = gj + dj[k], ni = gi + di[k];
            if (nj >= 0 && nj < Wd && ni >= 0 && ni < Wd) {
                int nc = soff + b * HWc + nj * Wd + ni;
                atomicMax(&g_lastAny[nc], seq);
                if (cls_ok) atomicOr(&g_maskA[3*nc + (cid >> 5)], 1u << (cid & 31));
            }
        }
    }
}

// One thread per objp element across all 3 scales. Each 256-block lies in one scale
// (307200, 384000, 403200 all divisible by 256) -> single atomicAdd per block.
__global__ __launch_bounds__(256) void k_obj(const float* __restrict__ o0,
                                             const float* __restrict__ o1,
                                             const float* __restrict__ o2) {
    __shared__ double sred[256];
    int n = blockIdx.x * 256 + threadIdx.x;  // grid = 1575*256 = 403200 exactly
    int s, loc, HW, soff;
    const float* out;
    if (n < OBJ_OFF1)      { s = 0; loc = n;            out = o0; HW = 6400; soff = 0; }
    else if (n < OBJ_OFF2) { s = 1; loc = n - OBJ_OFF1; out = o1; HW = 1600; soff = CELL_OFF1; }
    else                   { s = 2; loc = n - OBJ_OFF2; out = o2; HW = 400;  soff = CELL_OFF2; }
    int b = loc / (NA * HW);
    int r = loc % (NA * HW);
    int a = r / HW;
    int cij = r % HW;

    float x = out[(size_t)loc * 85 + 4];
    float contrib = softplusf(x);
    if (a == 0) {
        int cell = soff + b * HW + cij;
        float tv = g_lastMain[cell] ? 1.0f : (g_lastAny[cell] ? 0.5f : 0.0f);
        contrib -= x * tv;
    }
    sred[threadIdx.x] = (double)contrib;
    __syncthreads();
    for (int st = 128; st > 0; st >>= 1) {
        if (threadIdx.x < st) sred[threadIdx.x] += sred[threadIdx.x + st];
        __syncthreads();
    }
    if (threadIdx.x == 0) atomicAdd(&g_objsum[s], sred[0]);
}

// One thread per anchor-0 cell; only pos cells (lastMain>0) do real work.
__global__ __launch_bounds__(256) void k_pos(const float* __restrict__ o0,
                                             const float* __restrict__ o1,
                                             const float* __restrict__ o2) {
    __shared__ double sred[256];
    __shared__ int    sint[256];
    int n = blockIdx.x * 256 + threadIdx.x;  // grid = 525*256 = 134400 exactly
    int s, HW, soff;
    const float* out;
    if (n < CELL_OFF1)      { s = 0; soff = 0;         HW = 6400; out = o0; }
    else if (n < CELL_OFF2) { s = 1; soff = CELL_OFF1; HW = 1600; out = o1; }
    else                    { s = 2; soff = CELL_OFF2; HW = 400;  out = o2; }
    int loc = n - soff;
    int b = loc / HW;
    int cij = loc % HW;

    double bsum = 0.0, csum = 0.0;
    int np = 0;
    unsigned lm = g_lastMain[n];
    if (lm) {
        unsigned la = g_lastAny[n];
        float4 bt = g_bvec[b * NT + (int)(la - 1)];
        float sw  = g_weight[b * NT + (int)(lm - 1)];
        const float* cellp = out + ((size_t)(b * NA * HW) + (size_t)cij) * 85;

        float btv[4] = {bt.x, bt.y, bt.z, bt.w};
        float pb[4];
        float l1 = 0.0f;
        #pragma unroll
        for (int k = 0; k < 4; ++k) {
            float x = cellp[k];
            float pv = 1.0f / (1.0f + expf(-x));
            pb[k] = pv;
            float d = pv - btv[k];
            float ad = fabsf(d);
            l1 += (ad < 1.0f) ? (0.5f * d * d) : (ad - 0.5f);
        }
        l1 *= 0.25f;

        float ix1 = fmaxf(pb[0], bt.x), iy1 = fmaxf(pb[1], bt.y);
        float ix2 = fminf(pb[2], bt.z), iy2 = fminf(pb[3], bt.w);
        float inter = fmaxf(ix2 - ix1, 0.0f) * fmaxf(iy2 - iy1, 0.0f);
        float a1 = fmaxf(pb[2] - pb[0], 0.0f) * fmaxf(pb[3] - pb[1], 0.0f);
        float a2 = fmaxf(bt.z - bt.x, 0.0f) * fmaxf(bt.w - bt.y, 0.0f);
        float iou = inter / (a1 + a2 - inter + 1e-6f);
        bsum = (double)((l1 + 1.0f - iou) * sw);

        unsigned m0 = g_maskA[3*n], m1 = g_maskA[3*n+1], m2 = g_maskA[3*n+2];
        float cacc = 0.0f;
        #pragma unroll 4
        for (int c = 0; c < NCLS; ++c) {
            float x = cellp[5 + c];
            float sp = softplusf(x);
            unsigned bit = ((c < 32 ? (m0 >> c) : (c < 64 ? (m1 >> (c - 32)) : (m2 >> (c - 64)))) & 1u);
            cacc += sp - (bit ? x : 0.0f);
        }
        csum = (double)(cacc * (1.0f / (float)NCLS) * sw);
        np = 1;
    }

    // reduce bsum
    sred[threadIdx.x] = bsum; __syncthreads();
    for (int st = 128; st > 0; st >>= 1) {
        if (threadIdx.x < st) sred[threadIdx.x] += sred[threadIdx.x + st];
        __syncthreads();
    }
    if (threadIdx.x == 0 && sred[0] != 0.0) atomicAdd(&g_boxsum[s], sred[0]);
    __syncthreads();
    // reduce csum
    sred[threadIdx.x] = csum; __syncthreads();
    for (int st = 128; st > 0; st >>= 1) {
        if (threadIdx.x < st) sred[threadIdx.x] += sred[threadIdx.x + st];
        __syncthreads();
    }
    if (threadIdx.x == 0 && sred[0] != 0.0) atomicAdd(&g_clssum[s], sred[0]);
    // reduce npos
    sint[threadIdx.x] = np; __syncthreads();
    for (int st = 128; st > 0; st >>= 1) {
        if (threadIdx.x < st) sint[threadIdx.x] += sint[threadIdx.x + st];
        __syncthreads();
    }
    if (threadIdx.x == 0 && sint[0] != 0) atomicAdd(&g_npos[s], (unsigned)sint[0]);
}

__global__ void k_final(float* __restrict__ d_out) {
    if (threadIdx.x != 0 || blockIdx.x != 0) return;
    const double cells[3] = {307200.0, 76800.0, 19200.0};
    double bl = 0.0, ol = 0.0, cl = 0.0;
    for (int s = 0; s < 3; ++s) {
        ol += g_objsum[s] / cells[s];
        unsigned np = g_npos[s];
        if (np > 0u) {
            double denom = (double)np;
            bl += g_boxsum[s] / denom;
            cl += g_clssum[s] / denom;
        }
    }
    bl /= 3.0; ol /= 3.0; cl /= 3.0;
    double fin = 5.0 * bl + 1.0 * ol + 1.0 * cl;
    d_out[0] = (float)fin;
    d_out[1] = (float)bl;
    d_out[2] = (float)ol;
    d_out[3] = (float)cl;
}

extern "C" void kernel_launch(void* const* d_in, const int* in_sizes, int n_in,
                              void* d_out, int out_size, void* d_ws, size_t ws_size,
                              hipStream_t stream) {
    const float* o0 = (const float*)d_in[0];
    const float* o1 = (const float*)d_in[1];
    const float* o2 = (const float*)d_in[2];
    const float* tg = (const float*)d_in[3];
    float* outp = (float*)d_out;

    k_clear  <<<TOTCELLS / 256, 256, 0, stream>>>();
    k_scatter<<<(NB * NT + 255) / 256, 256, 0, stream>>>(tg);
    k_obj    <<<OBJ_TOT / 256, 256, 0, stream>>>(o0, o1, o2);
    k_pos    <<<TOTCELLS / 256, 256, 0, stream>>>(o0, o1, o2);
    k_final  <<<1, 64, 0, stream>>>(outp);
}

// Round 2
// 75.205 us; speedup vs baseline: 1.4280x; 1.4280x over previous
//
#include <hip/hip_runtime.h>
#include <math.h>

#define NCLS 80
#define NB 16
#define NA 3
#define NT 100

// grid-cell state layout: scale0 (80x80) cells [0,102400), scale1 (40x40)
// [102400,128000), scale2 (20x20) [128000,134400). index = off[s] + b*HW + j*W + i
static constexpr int TOTCELLS  = 134400;
static constexpr int CELL_OFF1 = 102400;
static constexpr int CELL_OFF2 = 128000;

// obj-channel element space: scale0 [0,307200), scale1 [,384000), scale2 [,403200)
static constexpr int OBJ_TOT  = 403200;
static constexpr int OBJ_OFF1 = 307200;
static constexpr int OBJ_OFF2 = 384000;

__device__ unsigned g_lastMain[TOTCELLS];   // (t+1) of last valid MAIN event, 0 = none
__device__ unsigned g_lastAny [TOTCELLS];   // (t+1) of last event of any kind, 0 = none
__device__ unsigned g_maskA   [TOTCELLS*3]; // 80-bit class OR mask
__device__ float4   g_bvec  [NB*NT];        // clipped box per target
__device__ float    g_weight[NB*NT];        // weight per target
__device__ double   g_objsum[3];
__device__ double   g_boxsum[3];
__device__ double   g_clssum[3];
__device__ unsigned g_npos  [3];
__device__ unsigned g_posCount;
__device__ unsigned g_posList[NB*NT];       // compacted positive cell indices

__device__ __forceinline__ float softplusf(float x) {
    // logaddexp(0,x) stable
    return fmaxf(x, 0.0f) + log1pf(expf(-fabsf(x)));
}

__global__ __launch_bounds__(256) void k_clear() {
    int i = blockIdx.x * 256 + threadIdx.x;  // grid = 525*256 = 134400 exactly
    g_lastMain[i] = 0u;
    g_lastAny[i]  = 0u;
    g_maskA[3*i+0] = 0u; g_maskA[3*i+1] = 0u; g_maskA[3*i+2] = 0u;
    if (i < 3) { g_objsum[i] = 0.0; g_boxsum[i] = 0.0; g_clssum[i] = 0.0; g_npos[i] = 0u; }
    if (i == 0) g_posCount = 0u;
}

// One thread per (b,t). Order-faithful via atomicMax on sequence = t+1.
__global__ __launch_bounds__(256) void k_scatter(const float* __restrict__ tgt) {
    int idx = blockIdx.x * 256 + threadIdx.x;
    if (idx >= NB * NT) return;
    int b = idx / NT, t = idx % NT;
    const float* p = tgt + (size_t)idx * 5;
    float x1 = fminf(fmaxf(p[0], 0.0f), 1.0f);
    float y1 = fminf(fmaxf(p[1], 0.0f), 1.0f);
    float x2 = fminf(fmaxf(p[2], 0.0f), 1.0f);
    float y2 = fminf(fmaxf(p[3], 0.0f), 1.0f);
    bool valid = (x2 > x1) && (y2 > y1);
    float area = (x2 - x1) * (y2 - y1);
    int sidx = (area <= 0.0025f) ? 0 : ((area <= 0.0225f) ? 1 : 2);
    int Wd = (sidx == 0) ? 80 : ((sidx == 1) ? 40 : 20);
    int HWc = Wd * Wd;
    int soff = (sidx == 0) ? 0 : ((sidx == 1) ? CELL_OFF1 : CELL_OFF2);

    int gi = (int)floorf(0.5f * (x1 + x2) * (float)Wd);
    int gj = (int)floorf(0.5f * (y1 + y2) * (float)Wd);
    gi = min(max(gi, 0), Wd - 1);
    gj = min(max(gj, 0), Wd - 1);

    int cid = (int)p[4];
    bool cls_ok = (cid >= 0) && (cid < NCLS);
    float smallness = 1.0f - fminf(1.0f, area / 0.0025f);
    float weight = 1.0f + fmaxf(0.0f, smallness);

    g_bvec[idx]   = make_float4(x1, y1, x2, y2);
    g_weight[idx] = weight;

    if (!valid) return;
    unsigned seq = (unsigned)(t + 1);
    int cell = soff + b * HWc + gj * Wd + gi;
    atomicMax(&g_lastMain[cell], seq);
    atomicMax(&g_lastAny[cell],  seq);
    if (cls_ok) atomicOr(&g_maskA[3*cell + (cid >> 5)], 1u << (cid & 31));

    if (area <= 0.0025f) {  // tiny -> 4 neighbors
        const int dj[4] = {-1, 1, 0, 0};
        const int di[4] = {0, 0, -1, 1};
        #pragma unroll
        for (int k = 0; k < 4; ++k) {
            int nj = gj + dj[k], ni = gi + di[k];
            if (nj >= 0 && nj < Wd && ni >= 0 && ni < Wd) {
                int nc = soff + b * HWc + nj * Wd + ni;
                atomicMax(&g_lastAny[nc], seq);
                if (cls_ok) atomicOr(&g_maskA[3*nc + (cid >> 5)], 1u << (cid & 31));
            }
        }
    }
}

// One thread per objp element across all 3 scales. Each 256-block lies in one scale
// (307200, 384000, 403200 all divisible by 256) -> single atomicAdd per block.
// Anchor-0 positive cells are compacted into g_posList here (after scatter).
__global__ __launch_bounds__(256) void k_obj(const float* __restrict__ o0,
                                             const float* __restrict__ o1,
                                             const float* __restrict__ o2) {
    __shared__ double sred[256];
    int n = blockIdx.x * 256 + threadIdx.x;  // grid = 1575*256 = 403200 exactly
    int s, loc, HW, soff;
    const float* out;
    if (n < OBJ_OFF1)      { s = 0; loc = n;            out = o0; HW = 6400; soff = 0; }
    else if (n < OBJ_OFF2) { s = 1; loc = n - OBJ_OFF1; out = o1; HW = 1600; soff = CELL_OFF1; }
    else                   { s = 2; loc = n - OBJ_OFF2; out = o2; HW = 400;  soff = CELL_OFF2; }
    int b = loc / (NA * HW);
    int r = loc % (NA * HW);
    int a = r / HW;
    int cij = r % HW;

    float x = out[(size_t)loc * 85 + 4];
    float contrib = softplusf(x);
    if (a == 0) {
        int cell = soff + b * HW + cij;
        unsigned lm = g_lastMain[cell];
        float tv = lm ? 1.0f : (g_lastAny[cell] ? 0.5f : 0.0f);
        contrib -= x * tv;
        if (lm) {
            unsigned slot = atomicAdd(&g_posCount, 1u);
            g_posList[slot] = (unsigned)cell;
            atomicAdd(&g_npos[s], 1u);
        }
    }
    sred[threadIdx.x] = (double)contrib;
    __syncthreads();
    for (int st = 128; st > 0; st >>= 1) {
        if (threadIdx.x < st) sred[threadIdx.x] += sred[threadIdx.x + st];
        __syncthreads();
    }
    if (threadIdx.x == 0) atomicAdd(&g_objsum[s], sred[0]);
}

// One WAVE per positive cell. Lane i holds channel i (and lane<21 channel 64+i):
// the whole 340B row in two coalesced loads; one softplus per lane.
__global__ __launch_bounds__(256) void k_poswork(const float* __restrict__ o0,
                                                 const float* __restrict__ o1,
                                                 const float* __restrict__ o2) {
    __shared__ double sB[4], sC[4];
    __shared__ int    sS[4];
    int wv   = threadIdx.x >> 6;
    int lane = threadIdx.x & 63;
    int w = blockIdx.x * 4 + wv;
    unsigned count = g_posCount;

    double bsum = 0.0, csum = 0.0;
    int sidx = -1;
    if (w < (int)count) {
        int n = (int)g_posList[w];
        int s, b, cij, HW;
        const float* out;
        if (n < CELL_OFF1)      { s = 0; HW = 6400; int l = n;             b = l / 6400; cij = l % 6400; out = o0; }
        else if (n < CELL_OFF2) { s = 1; HW = 1600; int l = n - CELL_OFF1; b = l / 1600; cij = l % 1600; out = o1; }
        else                    { s = 2; HW = 400;  int l = n - CELL_OFF2; b = l / 400;  cij = l % 400;  out = o2; }
        sidx = s;

        const float* base = out + ((size_t)(b * NA * HW) + (size_t)cij) * 85;
        float v0 = base[lane];
        float v1 = (lane < 21) ? base[64 + lane] : 0.0f;

        unsigned m0 = g_maskA[3*n], m1 = g_maskA[3*n+1], m2 = g_maskA[3*n+2];
        unsigned lm = g_lastMain[n], la = g_lastAny[n];
        float4 bt = g_bvec[b * NT + (int)(la - 1u)];
        float  sw = g_weight[b * NT + (int)(lm - 1u)];

        // per-lane class BCE: lane>=5 -> class lane-5 (0..58); lane<21 -> class lane+59 (59..79)
        float cl_ = 0.0f;
        if (lane >= 5) {
            int c = lane - 5;
            unsigned bit = ((c < 32) ? (m0 >> c) : (m1 >> (c - 32))) & 1u;
            cl_ += softplusf(v0) - (bit ? v0 : 0.0f);
        }
        if (lane < 21) {
            int c = lane + 59;
            unsigned bit = ((c < 64) ? (m1 >> (c - 32)) : (m2 >> (c - 64))) & 1u;
            cl_ += softplusf(v1) - (bit ? v1 : 0.0f);
        }

        // box regression values from lanes 0..3
        float pv = 1.0f / (1.0f + expf(-v0));
        float pb0 = __shfl(pv, 0), pb1 = __shfl(pv, 1), pb2 = __shfl(pv, 2), pb3 = __shfl(pv, 3);

        // wave reduce class sum
        #pragma unroll
        for (int off = 32; off > 0; off >>= 1) cl_ += __shfl_xor(cl_, off);

        if (lane == 0) {
            float btv[4] = {bt.x, bt.y, bt.z, bt.w};
            float pb[4]  = {pb0, pb1, pb2, pb3};
            float l1 = 0.0f;
            #pragma unroll
            for (int k = 0; k < 4; ++k) {
                float d = pb[k] - btv[k];
                float ad = fabsf(d);
                l1 += (ad < 1.0f) ? (0.5f * d * d) : (ad - 0.5f);
            }
            l1 *= 0.25f;
            float ix1 = fmaxf(pb0, bt.x), iy1 = fmaxf(pb1, bt.y);
            float ix2 = fminf(pb2, bt.z), iy2 = fminf(pb3, bt.w);
            float inter = fmaxf(ix2 - ix1, 0.0f) * fmaxf(iy2 - iy1, 0.0f);
            float a1 = fmaxf(pb2 - pb0, 0.0f) * fmaxf(pb3 - pb1, 0.0f);
            float a2 = fmaxf(bt.z - bt.x, 0.0f) * fmaxf(bt.w - bt.y, 0.0f);
            float iou = inter / (a1 + a2 - inter + 1e-6f);
            bsum = (double)((l1 + 1.0f - iou) * sw);
            csum = (double)(cl_ * (1.0f / (float)NCLS) * sw);
        }
    }

    if (lane == 0) { sB[wv] = bsum; sC[wv] = csum; sS[wv] = sidx; }
    __syncthreads();
    if (threadIdx.x == 0) {
        double accB[3] = {0.0, 0.0, 0.0};
        double accC[3] = {0.0, 0.0, 0.0};
        #pragma unroll
        for (int i = 0; i < 4; ++i) {
            int si = sS[i];
            if (si >= 0) { accB[si] += sB[i]; accC[si] += sC[i]; }
        }
        #pragma unroll
        for (int s2 = 0; s2 < 3; ++s2) {
            if (accB[s2] != 0.0) atomicAdd(&g_boxsum[s2], accB[s2]);
            if (accC[s2] != 0.0) atomicAdd(&g_clssum[s2], accC[s2]);
        }
    }
}

__global__ void k_final(float* __restrict__ d_out) {
    if (threadIdx.x != 0 || blockIdx.x != 0) return;
    const double cells[3] = {307200.0, 76800.0, 19200.0};
    double bl = 0.0, ol = 0.0, cl = 0.0;
    for (int s = 0; s < 3; ++s) {
        ol += g_objsum[s] / cells[s];
        unsigned np = g_npos[s];
        if (np > 0u) {
            double denom = (double)np;
            bl += g_boxsum[s] / denom;
            cl += g_clssum[s] / denom;
        }
    }
    bl /= 3.0; ol /= 3.0; cl /= 3.0;
    double fin = 5.0 * bl + 1.0 * ol + 1.0 * cl;
    d_out[0] = (float)fin;
    d_out[1] = (float)bl;
    d_out[2] = (float)ol;
    d_out[3] = (float)cl;
}

extern "C" void kernel_launch(void* const* d_in, const int* in_sizes, int n_in,
                              void* d_out, int out_size, void* d_ws, size_t ws_size,
                              hipStream_t stream) {
    const float* o0 = (const float*)d_in[0];
    const float* o1 = (const float*)d_in[1];
    const float* o2 = (const float*)d_in[2];
    const float* tg = (const float*)d_in[3];
    float* outp = (float*)d_out;

    k_clear   <<<TOTCELLS / 256, 256, 0, stream>>>();
    k_scatter <<<(NB * NT + 255) / 256, 256, 0, stream>>>(tg);
    k_obj     <<<OBJ_TOT / 256, 256, 0, stream>>>(o0, o1, o2);
    k_poswork <<<(NB * NT + 3) / 4, 256, 0, stream>>>(o0, o1, o2);
    k_final   <<<1, 64, 0, stream>>>(outp);
}

// Round 3
// 62.360 us; speedup vs baseline: 1.7222x; 1.2060x over previous
//
#include <hip/hip_runtime.h>
#include <math.h>

#define NCLS 80
#define NB 16
#define NA 3
#define NT 100

// grid-cell state layout: scale0 (80x80) cells [0,102400), scale1 (40x40)
// [102400,128000), scale2 (20x20) [128000,134400). index = off[s] + b*HW + j*W + i
static constexpr int TOTCELLS  = 134400;
static constexpr int CELL_OFF1 = 102400;
static constexpr int CELL_OFF2 = 128000;

// obj-channel element space: scale0 [0,307200), scale1 [,384000), scale2 [,403200)
static constexpr int OBJ_TOT  = 403200;   // == 3*TOTCELLS (used for maskA clear too)
static constexpr int OBJ_OFF1 = 307200;
static constexpr int OBJ_OFF2 = 384000;

static constexpr int K1_BLOCKS = OBJ_TOT / 256;   // 1575
static constexpr int K4_BLOCKS = 400;             // 1600 waves >= posCount

__device__ unsigned g_lastMain[TOTCELLS];   // (t+1) of last valid MAIN event, 0 = none
__device__ unsigned g_lastAny [TOTCELLS];   // (t+1) of last event of any kind, 0 = none
__device__ unsigned g_maskA   [TOTCELLS*3]; // 80-bit class OR mask
__device__ float4   g_bvec  [NB*NT];        // clipped box per target
__device__ float    g_weight[NB*NT];        // weight per target
__device__ double   g_partial[K1_BLOCKS];   // per-block softplus partial (overwrite, no atomics)
__device__ double   g_objsum[3];
__device__ double   g_objcorr[3];
__device__ double   g_boxsum[3];
__device__ double   g_clssum[3];
__device__ unsigned g_npos  [3];
__device__ unsigned g_posCount;
__device__ unsigned g_posList[NB*NT];       // compacted positive cell indices
__device__ unsigned g_done;

__device__ __forceinline__ float softplusf(float x) {
    return fmaxf(x, 0.0f) + log1pf(expf(-fabsf(x)));   // stable logaddexp(0,x)
}

__device__ __forceinline__ double wred64(double v) {
    #pragma unroll
    for (int o = 32; o > 0; o >>= 1) v += __shfl_xor(v, o);
    return v;
}

// ---------------- K1: clear state + target-independent sum of softplus(objp) ---------
__global__ __launch_bounds__(256) void k1_clear_obj(const float* __restrict__ o0,
                                                    const float* __restrict__ o1,
                                                    const float* __restrict__ o2) {
    __shared__ double sw4[4];
    int n = blockIdx.x * 256 + threadIdx.x;   // grid covers [0, 403200) exactly
    g_maskA[n] = 0u;
    if (n < TOTCELLS) { g_lastMain[n] = 0u; g_lastAny[n] = 0u; }
    if (n == 0) {
        #pragma unroll
        for (int s = 0; s < 3; ++s) {
            g_objsum[s] = 0.0; g_objcorr[s] = 0.0;
            g_boxsum[s] = 0.0; g_clssum[s] = 0.0;
            g_npos[s] = 0u;
        }
        g_posCount = 0u; g_done = 0u;
    }
    const float* out; int loc;
    if (n < OBJ_OFF1)      { out = o0; loc = n; }
    else if (n < OBJ_OFF2) { out = o1; loc = n - OBJ_OFF1; }
    else                   { out = o2; loc = n - OBJ_OFF2; }
    float x = out[(size_t)loc * 85 + 4];
    double v = wred64((double)softplusf(x));
    if ((threadIdx.x & 63) == 0) sw4[threadIdx.x >> 6] = v;
    __syncthreads();
    if (threadIdx.x == 0) g_partial[blockIdx.x] = sw4[0] + sw4[1] + sw4[2] + sw4[3];
}

// ---------------- K2: order-faithful scatter via atomicMax(seq) ----------------------
__global__ __launch_bounds__(256) void k_scatter(const float* __restrict__ tgt) {
    int idx = blockIdx.x * 256 + threadIdx.x;
    if (idx >= NB * NT) return;
    int b = idx / NT, t = idx % NT;
    const float* p = tgt + (size_t)idx * 5;
    float x1 = fminf(fmaxf(p[0], 0.0f), 1.0f);
    float y1 = fminf(fmaxf(p[1], 0.0f), 1.0f);
    float x2 = fminf(fmaxf(p[2], 0.0f), 1.0f);
    float y2 = fminf(fmaxf(p[3], 0.0f), 1.0f);
    bool valid = (x2 > x1) && (y2 > y1);
    float area = (x2 - x1) * (y2 - y1);
    int sidx = (area <= 0.0025f) ? 0 : ((area <= 0.0225f) ? 1 : 2);
    int Wd = (sidx == 0) ? 80 : ((sidx == 1) ? 40 : 20);
    int HWc = Wd * Wd;
    int soff = (sidx == 0) ? 0 : ((sidx == 1) ? CELL_OFF1 : CELL_OFF2);

    int gi = (int)floorf(0.5f * (x1 + x2) * (float)Wd);
    int gj = (int)floorf(0.5f * (y1 + y2) * (float)Wd);
    gi = min(max(gi, 0), Wd - 1);
    gj = min(max(gj, 0), Wd - 1);

    int cid = (int)p[4];
    bool cls_ok = (cid >= 0) && (cid < NCLS);
    float smallness = 1.0f - fminf(1.0f, area / 0.0025f);
    float weight = 1.0f + fmaxf(0.0f, smallness);

    g_bvec[idx]   = make_float4(x1, y1, x2, y2);
    g_weight[idx] = weight;

    if (!valid) return;
    unsigned seq = (unsigned)(t + 1);
    int cell = soff + b * HWc + gj * Wd + gi;
    atomicMax(&g_lastMain[cell], seq);
    atomicMax(&g_lastAny[cell],  seq);
    if (cls_ok) atomicOr(&g_maskA[3*cell + (cid >> 5)], 1u << (cid & 31));

    if (area <= 0.0025f) {  // tiny -> 4 neighbors
        const int dj[4] = {-1, 1, 0, 0};
        const int di[4] = {0, 0, -1, 1};
        #pragma unroll
        for (int k = 0; k < 4; ++k) {
            int nj = gj + dj[k], ni = gi + di[k];
            if (nj >= 0 && nj < Wd && ni >= 0 && ni < Wd) {
                int nc = soff + b * HWc + nj * Wd + ni;
                atomicMax(&g_lastAny[nc], seq);
                if (cls_ok) atomicOr(&g_maskA[3*nc + (cid >> 5)], 1u << (cid & 31));
            }
        }
    }
}

// ---------------- K3: winner pass — obj corrections + pos-cell compaction ------------
__global__ __launch_bounds__(256) void k3_winner(const float* __restrict__ o0,
                                                 const float* __restrict__ o1,
                                                 const float* __restrict__ o2,
                                                 const float* __restrict__ tgt) {
    __shared__ double sw4[3][4];
    int idx = blockIdx.x * 256 + threadIdx.x;
    double corr[3] = {0.0, 0.0, 0.0};
    if (idx < NB * NT) {
        int b = idx / NT, t = idx % NT;
        const float* p = tgt + (size_t)idx * 5;
        float x1 = fminf(fmaxf(p[0], 0.0f), 1.0f);
        float y1 = fminf(fmaxf(p[1], 0.0f), 1.0f);
        float x2 = fminf(fmaxf(p[2], 0.0f), 1.0f);
        float y2 = fminf(fmaxf(p[3], 0.0f), 1.0f);
        bool valid = (x2 > x1) && (y2 > y1);
        if (valid) {
            float area = (x2 - x1) * (y2 - y1);
            int sidx = (area <= 0.0025f) ? 0 : ((area <= 0.0225f) ? 1 : 2);
            int Wd = (sidx == 0) ? 80 : ((sidx == 1) ? 40 : 20);
            int HWc = Wd * Wd;
            int soff = (sidx == 0) ? 0 : ((sidx == 1) ? CELL_OFF1 : CELL_OFF2);
            const float* out = (sidx == 0) ? o0 : ((sidx == 1) ? o1 : o2);
            int gi = (int)floorf(0.5f * (x1 + x2) * (float)Wd);
            int gj = (int)floorf(0.5f * (y1 + y2) * (float)Wd);
            gi = min(max(gi, 0), Wd - 1);
            gj = min(max(gj, 0), Wd - 1);
            unsigned seq = (unsigned)(t + 1);
            int cell = soff + b * HWc + gj * Wd + gi;
            if (g_lastMain[cell] == seq) {   // unique main winner of this cell
                unsigned slot = atomicAdd(&g_posCount, 1u);
                g_posList[slot] = (unsigned)cell;
                atomicAdd(&g_npos[sidx], 1u);
                float x = out[((size_t)(b * NA * HWc) + (size_t)(gj * Wd + gi)) * 85 + 4];
                corr[sidx] -= (double)x;     // tv = 1.0
            }
            if (area <= 0.0025f) {
                const int dj[4] = {-1, 1, 0, 0};
                const int di[4] = {0, 0, -1, 1};
                #pragma unroll
                for (int k = 0; k < 4; ++k) {
                    int nj = gj + dj[k], ni = gi + di[k];
                    if (nj >= 0 && nj < Wd && ni >= 0 && ni < Wd) {
                        int nc = soff + b * HWc + nj * Wd + ni;
                        if (g_lastMain[nc] == 0u && g_lastAny[nc] == seq) { // neighbor-only winner
                            float x = out[((size_t)(b * NA * HWc) + (size_t)(nj * Wd + ni)) * 85 + 4];
                            corr[sidx] -= 0.5 * (double)x;   // tv = 0.5
                        }
                    }
                }
            }
        }
    }
    #pragma unroll
    for (int s = 0; s < 3; ++s) {
        double r = wred64(corr[s]);
        if ((threadIdx.x & 63) == 0) sw4[s][threadIdx.x >> 6] = r;
    }
    __syncthreads();
    if (threadIdx.x == 0) {
        #pragma unroll
        for (int s = 0; s < 3; ++s) {
            double r = sw4[s][0] + sw4[s][1] + sw4[s][2] + sw4[s][3];
            if (r != 0.0) atomicAdd(&g_objcorr[s], r);
        }
    }
}

// ---------------- K4: wave-per-pos-cell box/cls + partial fold + finalize ------------
__global__ __launch_bounds__(256) void k4_poswork(const float* __restrict__ o0,
                                                  const float* __restrict__ o1,
                                                  const float* __restrict__ o2,
                                                  float* __restrict__ d_out) {
    __shared__ double sB[4], sC[4];
    __shared__ int    sS[4];
    int wv   = threadIdx.x >> 6;
    int lane = threadIdx.x & 63;
    int w = blockIdx.x * 4 + wv;
    unsigned count = g_posCount;

    double bsum = 0.0, csum = 0.0;
    int sidx = -1;
    if (w < (int)count) {
        int n = (int)g_posList[w];
        int s, b, cij, HW;
        const float* out;
        if (n < CELL_OFF1)      { s = 0; HW = 6400; int l = n;             b = l / 6400; cij = l % 6400; out = o0; }
        else if (n < CELL_OFF2) { s = 1; HW = 1600; int l = n - CELL_OFF1; b = l / 1600; cij = l % 1600; out = o1; }
        else                    { s = 2; HW = 400;  int l = n - CELL_OFF2; b = l / 400;  cij = l % 400;  out = o2; }
        sidx = s;

        const float* base = out + ((size_t)(b * NA * HW) + (size_t)cij) * 85;
        float v0 = base[lane];
        float v1 = (lane < 21) ? base[64 + lane] : 0.0f;

        unsigned m0 = g_maskA[3*n], m1 = g_maskA[3*n+1], m2 = g_maskA[3*n+2];
        unsigned lm = g_lastMain[n], la = g_lastAny[n];
        float4 bt = g_bvec[b * NT + (int)(la - 1u)];
        float  sw = g_weight[b * NT + (int)(lm - 1u)];

        // per-lane class BCE: lane>=5 -> class lane-5 (0..58); lane<21 -> class lane+59
        float cl_ = 0.0f;
        if (lane >= 5) {
            int c = lane - 5;
            unsigned bit = ((c < 32) ? (m0 >> c) : (m1 >> (c - 32))) & 1u;
            cl_ += softplusf(v0) - (bit ? v0 : 0.0f);
        }
        if (lane < 21) {
            int c = lane + 59;
            unsigned bit = ((c < 64) ? (m1 >> (c - 32)) : (m2 >> (c - 64))) & 1u;
            cl_ += softplusf(v1) - (bit ? v1 : 0.0f);
        }

        float pv = 1.0f / (1.0f + expf(-v0));
        float pb0 = __shfl(pv, 0), pb1 = __shfl(pv, 1), pb2 = __shfl(pv, 2), pb3 = __shfl(pv, 3);

        #pragma unroll
        for (int off = 32; off > 0; off >>= 1) cl_ += __shfl_xor(cl_, off);

        if (lane == 0) {
            float btv[4] = {bt.x, bt.y, bt.z, bt.w};
            float pb[4]  = {pb0, pb1, pb2, pb3};
            float l1 = 0.0f;
            #pragma unroll
            for (int k = 0; k < 4; ++k) {
                float d = pb[k] - btv[k];
                float ad = fabsf(d);
                l1 += (ad < 1.0f) ? (0.5f * d * d) : (ad - 0.5f);
            }
            l1 *= 0.25f;
            float ix1 = fmaxf(pb0, bt.x), iy1 = fmaxf(pb1, bt.y);
            float ix2 = fminf(pb2, bt.z), iy2 = fminf(pb3, bt.w);
            float inter = fmaxf(ix2 - ix1, 0.0f) * fmaxf(iy2 - iy1, 0.0f);
            float a1 = fmaxf(pb2 - pb0, 0.0f) * fmaxf(pb3 - pb1, 0.0f);
            float a2 = fmaxf(bt.z - bt.x, 0.0f) * fmaxf(bt.w - bt.y, 0.0f);
            float iou = inter / (a1 + a2 - inter + 1e-6f);
            bsum = (double)((l1 + 1.0f - iou) * sw);
            csum = (double)(cl_ * (1.0f / (float)NCLS) * sw);
        }
    }

    if (lane == 0) { sB[wv] = bsum; sC[wv] = csum; sS[wv] = sidx; }
    __syncthreads();
    if (threadIdx.x == 0) {
        double accB[3] = {0.0, 0.0, 0.0};
        double accC[3] = {0.0, 0.0, 0.0};
        #pragma unroll
        for (int i = 0; i < 4; ++i) {
            int si = sS[i];
            if (si >= 0) { accB[si] += sB[i]; accC[si] += sC[i]; }
        }
        #pragma unroll
        for (int s2 = 0; s2 < 3; ++s2) {
            if (accB[s2] != 0.0) atomicAdd(&g_boxsum[s2], accB[s2]);
            if (accC[s2] != 0.0) atomicAdd(&g_clssum[s2], accC[s2]);
        }
        // fold softplus partials: indices bid, bid+400, bid+800, bid+1200
        double accP[3] = {0.0, 0.0, 0.0};
        for (int k = blockIdx.x; k < K1_BLOCKS; k += K4_BLOCKS) {
            int s2 = (k < 1200) ? 0 : ((k < 1500) ? 1 : 2);
            accP[s2] += g_partial[k];
        }
        #pragma unroll
        for (int s2 = 0; s2 < 3; ++s2)
            if (accP[s2] != 0.0) atomicAdd(&g_objsum[s2], accP[s2]);

        __threadfence();
        unsigned old = atomicAdd(&g_done, 1u);
        if (old == (unsigned)(gridDim.x - 1)) {   // last block finalizes
            const double cells[3] = {307200.0, 76800.0, 19200.0};
            double bl = 0.0, ol = 0.0, cl = 0.0;
            for (int s = 0; s < 3; ++s) {
                double os = atomicAdd(&g_objsum[s], 0.0) + atomicAdd(&g_objcorr[s], 0.0);
                ol += os / cells[s];
                unsigned np = atomicAdd(&g_npos[s], 0u);
                if (np > 0u) {
                    double denom = (double)np;
                    bl += atomicAdd(&g_boxsum[s], 0.0) / denom;
                    cl += atomicAdd(&g_clssum[s], 0.0) / denom;
                }
            }
            bl /= 3.0; ol /= 3.0; cl /= 3.0;
            double fin = 5.0 * bl + 1.0 * ol + 1.0 * cl;
            d_out[0] = (float)fin;
            d_out[1] = (float)bl;
            d_out[2] = (float)ol;
            d_out[3] = (float)cl;
        }
    }
}

extern "C" void kernel_launch(void* const* d_in, const int* in_sizes, int n_in,
                              void* d_out, int out_size, void* d_ws, size_t ws_size,
                              hipStream_t stream) {
    const float* o0 = (const float*)d_in[0];
    const float* o1 = (const float*)d_in[1];
    const float* o2 = (const float*)d_in[2];
    const float* tg = (const float*)d_in[3];
    float* outp = (float*)d_out;

    k1_clear_obj<<<K1_BLOCKS, 256, 0, stream>>>(o0, o1, o2);
    k_scatter   <<<(NB * NT + 255) / 256, 256, 0, stream>>>(tg);
    k3_winner   <<<(NB * NT + 255) / 256, 256, 0, stream>>>(o0, o1, o2, tg);
    k4_poswork  <<<K4_BLOCKS, 256, 0, stream>>>(o0, o1, o2, outp);
}